// Round 4
// baseline (149.932 us; speedup 1.0000x reference)
//
#include <hip/hip_runtime.h>

// Noise_Cell: out[i] = G[idx[i]] * (1 + 0.03 * eps[i])
// G: 8-entry f32 LUT; eps: f32 [64,1024,1024]; idx: i32 in [0,8).
// Memory-bound streaming. R1: latency-bound (VGPR=8, LDS gather dep).
// R3: cndmask-register LUT + unroll x4 + nt stores -> 143 us.
//     Steady state: FETCH 268 MB vs 537 MB logical reads => L3 serves ~50%
//     of inputs; HBM-side floor ~85 us. Still issue-limited.
// R4: UNROLL 4 -> 8 (16 loads in flight per wave before any waitcnt).

typedef float f32x4 __attribute__((ext_vector_type(4)));
typedef int   i32x4 __attribute__((ext_vector_type(4)));

constexpr float NOISE_PARAM = 0.03f;
constexpr int BLOCK  = 256;
constexpr int UNROLL = 8;   // float4s per thread

// 3-bit select from 8 uniform (SGPR-resident) values: 7 v_cndmask.
__device__ __forceinline__ float sel8(int x,
    float g0, float g1, float g2, float g3,
    float g4, float g5, float g6, float g7)
{
    float a  = (x & 1) ? g1 : g0;
    float b  = (x & 1) ? g3 : g2;
    float c  = (x & 1) ? g5 : g4;
    float d  = (x & 1) ? g7 : g6;
    float ab = (x & 2) ? b : a;
    float cd = (x & 2) ? d : c;
    return     (x & 4) ? cd : ab;
}

__global__ __launch_bounds__(BLOCK) void noise_cell_kernel(
    const float* __restrict__ G,
    const f32x4* __restrict__ e4,
    const i32x4* __restrict__ i4,
    f32x4*       __restrict__ o4,
    long long n4)   // number of float4 elements
{
    // Uniform loads -> s_load into SGPRs.
    const float g0 = G[0], g1 = G[1], g2 = G[2], g3 = G[3];
    const float g4 = G[4], g5 = G[5], g6 = G[6], g7 = G[7];

    long long base = (long long)blockIdx.x * (BLOCK * UNROLL) + threadIdx.x;

    if (base + (UNROLL - 1) * BLOCK < n4) {
        // Fast path: full tile. Issue all 16 loads before any use.
        f32x4 e[UNROLL];
        i32x4 x[UNROLL];
#pragma unroll
        for (int u = 0; u < UNROLL; ++u) e[u] = e4[base + (long long)u * BLOCK];
#pragma unroll
        for (int u = 0; u < UNROLL; ++u) x[u] = i4[base + (long long)u * BLOCK];
#pragma unroll
        for (int u = 0; u < UNROLL; ++u) {
            f32x4 o;
            o.x = sel8(x[u].x, g0,g1,g2,g3,g4,g5,g6,g7) * (1.0f + NOISE_PARAM * e[u].x);
            o.y = sel8(x[u].y, g0,g1,g2,g3,g4,g5,g6,g7) * (1.0f + NOISE_PARAM * e[u].y);
            o.z = sel8(x[u].z, g0,g1,g2,g3,g4,g5,g6,g7) * (1.0f + NOISE_PARAM * e[u].z);
            o.w = sel8(x[u].w, g0,g1,g2,g3,g4,g5,g6,g7) * (1.0f + NOISE_PARAM * e[u].w);
            __builtin_nontemporal_store(o, &o4[base + (long long)u * BLOCK]);
        }
    } else {
        // Edge tile: per-access guard.
#pragma unroll
        for (int u = 0; u < UNROLL; ++u) {
            long long i = base + (long long)u * BLOCK;
            if (i < n4) {
                f32x4 e = e4[i];
                i32x4 x = i4[i];
                f32x4 o;
                o.x = sel8(x.x, g0,g1,g2,g3,g4,g5,g6,g7) * (1.0f + NOISE_PARAM * e.x);
                o.y = sel8(x.y, g0,g1,g2,g3,g4,g5,g6,g7) * (1.0f + NOISE_PARAM * e.y);
                o.z = sel8(x.z, g0,g1,g2,g3,g4,g5,g6,g7) * (1.0f + NOISE_PARAM * e.z);
                o.w = sel8(x.w, g0,g1,g2,g3,g4,g5,g6,g7) * (1.0f + NOISE_PARAM * e.w);
                __builtin_nontemporal_store(o, &o4[i]);
            }
        }
    }
}

// Scalar tail for n % 4 remainder (none at 64*1024*1024, kept for generality).
__global__ void noise_cell_tail(
    const float* __restrict__ G,
    const float* __restrict__ eps,
    const int*   __restrict__ idx,
    float*       __restrict__ out,
    long long start, long long n)
{
    const float g0 = G[0], g1 = G[1], g2 = G[2], g3 = G[3];
    const float g4 = G[4], g5 = G[5], g6 = G[6], g7 = G[7];
    long long i = start + blockIdx.x * (long long)blockDim.x + threadIdx.x;
    if (i < n) {
        out[i] = sel8(idx[i], g0,g1,g2,g3,g4,g5,g6,g7)
                 * (1.0f + NOISE_PARAM * eps[i]);
    }
}

extern "C" void kernel_launch(void* const* d_in, const int* in_sizes, int n_in,
                              void* d_out, int out_size, void* d_ws, size_t ws_size,
                              hipStream_t stream) {
    // setup_inputs() dict order: G (8 f32), eps (f32), idx (i32)
    const float* G   = (const float*)d_in[0];
    const float* eps = (const float*)d_in[1];
    const int*   idx = (const int*)d_in[2];
    float*       out = (float*)d_out;

    long long n  = (long long)in_sizes[1];   // 67108864
    long long n4 = n / 4;                    // 16777216

    long long per_block = (long long)BLOCK * UNROLL;          // 2048 float4s
    int grid = (int)((n4 + per_block - 1) / per_block);       // 8192
    if (grid > 0) {
        noise_cell_kernel<<<grid, BLOCK, 0, stream>>>(
            G, (const f32x4*)eps, (const i32x4*)idx, (f32x4*)out, n4);
    }

    long long rem = n - n4 * 4;
    if (rem > 0) {
        int tgrid = (int)((rem + BLOCK - 1) / BLOCK);
        noise_cell_tail<<<tgrid, BLOCK, 0, stream>>>(G, eps, idx, out, n4 * 4, n);
    }
}

// Round 5
// 115.679 us; speedup vs baseline: 1.2961x; 1.2961x over previous
//
#include <hip/hip_runtime.h>

// Noise_Cell: out[i] = G[idx[i]] * (1 + 0.03 * eps[i])
// G: 8-entry f32 LUT; eps: f32 [64,1024,1024]; idx: i32 in [0,8).
// Memory-bound streaming. History:
//   R1 160us: LDS gather, UNROLL=1 (latency-bound, VGPR=8).
//   R3 143us: cndmask-register LUT + unroll x4 + nt stores.
//   R4 150us: UNROLL=8 REGRESSED (compiler re-serialized, VGPR=36).
// Steady state (R3/R4 counters): FETCH==eps size exactly -> idx is ~100%
// L3-resident, eps streams HBM, out streams HBM. Traffic already optimal
// (537 MB HBM + 268 MB L3 per replay). R5: nt-LOAD eps so its zero-reuse
// lines stop allocating/churning L3; revert to UNROLL=4.

typedef float f32x4 __attribute__((ext_vector_type(4)));
typedef int   i32x4 __attribute__((ext_vector_type(4)));

constexpr float NOISE_PARAM = 0.03f;
constexpr int BLOCK  = 256;
constexpr int UNROLL = 4;   // float4s per thread

// 3-bit select from 8 uniform (SGPR-resident) values: 7 v_cndmask.
__device__ __forceinline__ float sel8(int x,
    float g0, float g1, float g2, float g3,
    float g4, float g5, float g6, float g7)
{
    float a  = (x & 1) ? g1 : g0;
    float b  = (x & 1) ? g3 : g2;
    float c  = (x & 1) ? g5 : g4;
    float d  = (x & 1) ? g7 : g6;
    float ab = (x & 2) ? b : a;
    float cd = (x & 2) ? d : c;
    return     (x & 4) ? cd : ab;
}

__global__ __launch_bounds__(BLOCK) void noise_cell_kernel(
    const float* __restrict__ G,
    const f32x4* __restrict__ e4,
    const i32x4* __restrict__ i4,
    f32x4*       __restrict__ o4,
    long long n4)   // number of float4 elements
{
    // Uniform loads -> s_load into SGPRs.
    const float g0 = G[0], g1 = G[1], g2 = G[2], g3 = G[3];
    const float g4 = G[4], g5 = G[5], g6 = G[6], g7 = G[7];

    long long base = (long long)blockIdx.x * (BLOCK * UNROLL) + threadIdx.x;

    if (base + (UNROLL - 1) * BLOCK < n4) {
        // Fast path: full tile.
        f32x4 e[UNROLL];
        i32x4 x[UNROLL];
#pragma unroll
        for (int u = 0; u < UNROLL; ++u)
            e[u] = __builtin_nontemporal_load(&e4[base + (long long)u * BLOCK]);
#pragma unroll
        for (int u = 0; u < UNROLL; ++u)
            x[u] = i4[base + (long long)u * BLOCK];   // idx: keep L3-cached
#pragma unroll
        for (int u = 0; u < UNROLL; ++u) {
            f32x4 o;
            o.x = sel8(x[u].x, g0,g1,g2,g3,g4,g5,g6,g7) * (1.0f + NOISE_PARAM * e[u].x);
            o.y = sel8(x[u].y, g0,g1,g2,g3,g4,g5,g6,g7) * (1.0f + NOISE_PARAM * e[u].y);
            o.z = sel8(x[u].z, g0,g1,g2,g3,g4,g5,g6,g7) * (1.0f + NOISE_PARAM * e[u].z);
            o.w = sel8(x[u].w, g0,g1,g2,g3,g4,g5,g6,g7) * (1.0f + NOISE_PARAM * e[u].w);
            __builtin_nontemporal_store(o, &o4[base + (long long)u * BLOCK]);
        }
    } else {
        // Edge tile: per-access guard.
#pragma unroll
        for (int u = 0; u < UNROLL; ++u) {
            long long i = base + (long long)u * BLOCK;
            if (i < n4) {
                f32x4 e = __builtin_nontemporal_load(&e4[i]);
                i32x4 x = i4[i];
                f32x4 o;
                o.x = sel8(x.x, g0,g1,g2,g3,g4,g5,g6,g7) * (1.0f + NOISE_PARAM * e.x);
                o.y = sel8(x.y, g0,g1,g2,g3,g4,g5,g6,g7) * (1.0f + NOISE_PARAM * e.y);
                o.z = sel8(x.z, g0,g1,g2,g3,g4,g5,g6,g7) * (1.0f + NOISE_PARAM * e.z);
                o.w = sel8(x.w, g0,g1,g2,g3,g4,g5,g6,g7) * (1.0f + NOISE_PARAM * e.w);
                __builtin_nontemporal_store(o, &o4[i]);
            }
        }
    }
}

// Scalar tail for n % 4 remainder (none at 64*1024*1024, kept for generality).
__global__ void noise_cell_tail(
    const float* __restrict__ G,
    const float* __restrict__ eps,
    const int*   __restrict__ idx,
    float*       __restrict__ out,
    long long start, long long n)
{
    const float g0 = G[0], g1 = G[1], g2 = G[2], g3 = G[3];
    const float g4 = G[4], g5 = G[5], g6 = G[6], g7 = G[7];
    long long i = start + blockIdx.x * (long long)blockDim.x + threadIdx.x;
    if (i < n) {
        out[i] = sel8(idx[i], g0,g1,g2,g3,g4,g5,g6,g7)
                 * (1.0f + NOISE_PARAM * eps[i]);
    }
}

extern "C" void kernel_launch(void* const* d_in, const int* in_sizes, int n_in,
                              void* d_out, int out_size, void* d_ws, size_t ws_size,
                              hipStream_t stream) {
    // setup_inputs() dict order: G (8 f32), eps (f32), idx (i32)
    const float* G   = (const float*)d_in[0];
    const float* eps = (const float*)d_in[1];
    const int*   idx = (const int*)d_in[2];
    float*       out = (float*)d_out;

    long long n  = (long long)in_sizes[1];   // 67108864
    long long n4 = n / 4;                    // 16777216

    long long per_block = (long long)BLOCK * UNROLL;          // 1024 float4s
    int grid = (int)((n4 + per_block - 1) / per_block);       // 16384
    if (grid > 0) {
        noise_cell_kernel<<<grid, BLOCK, 0, stream>>>(
            G, (const f32x4*)eps, (const i32x4*)idx, (f32x4*)out, n4);
    }

    long long rem = n - n4 * 4;
    if (rem > 0) {
        int tgrid = (int)((rem + BLOCK - 1) / BLOCK);
        noise_cell_tail<<<tgrid, BLOCK, 0, stream>>>(G, eps, idx, out, n4 * 4, n);
    }
}